// Round 5
// baseline (174.072 us; speedup 1.0000x reference)
//
#include <hip/hip_runtime.h>
#include <float.h>
#include <math.h>
#include <stdint.h>

// VQ-VAE VectorQuantizer — round 5: 8-wave blocks, 2 blocks/CU, no spills.
//
// R4 failed: __launch_bounds__(1024,4) forced VGPR=64 < ~100 live regs ->
// scratch spills (+34MB FETCH / +68MB WRITE), and 128KB LDS -> 1 block/CU.
// R5: 512 threads, cap 128 VGPR (fits), 2x32KB dbuf -> 2 blocks/CU.
//
// vq_main5: grid 512 x 512thr. Block = 64 z. Wave (zhalf, cq): 32 z (2 B-sets)
//   x 256 codes. Chunk = 4 tiles (1 per cq) = 32 KB, double-buffered DMA.
//   score[k][n] = wsq[k] - 2 w_k.z_n (MFMA);  loss_n = min_score + ||z_n||^2.
//
// ws: [0,4096) wsq f32 | [4096,8192) counts u32 | [8192,8200) loss f32, done u32
//     [16384, +524288) cbfrag bf16

#define NB   32
#define NC   256
#define NHW  1024
#define NK   1024
#define NELEM (NB*NC*NHW)
#define GRID_MAIN 512

typedef __attribute__((ext_vector_type(8))) short bf16x8;
typedef __attribute__((ext_vector_type(4))) float f32x4;

__device__ __forceinline__ unsigned short f2bf(float f) {   // RTN fp32->bf16
    unsigned u = __float_as_uint(f);
    u += 0x7FFFu + ((u >> 16) & 1u);
    return (unsigned short)(u >> 16);
}

// ---------------- K1: prep = wsq + pack + zero ----------------
__global__ __launch_bounds__(256) void vq_prep(const float* __restrict__ w,
                                               float* __restrict__ wsq,
                                               unsigned short* __restrict__ cb,
                                               unsigned int* __restrict__ counts,
                                               unsigned int* __restrict__ lossdone) {
    const int tid = threadIdx.x, b = blockIdx.x;
    const int lane = tid & 63, wv = tid >> 6;
    {   // wsq for code k = b*4 + wv
        const int k = b * 4 + wv;
        const float* row = w + k * NC;
        float s = 0.f;
#pragma unroll
        for (int p = 0; p < 4; ++p) { float v = row[lane + p * 64]; s = fmaf(v, v, s); }
#pragma unroll
        for (int off = 32; off; off >>= 1) s += __shfl_down(s, off, 64);
        if (lane == 0) wsq[k] = s;
    }
    // pack one 16B A-frag piece per thread (blocks 0..127)
    const int gt = b * 256 + tid;
    if (gt < 32768) {
        const int t = gt >> 9, p = gt & 511;
        const int cc = p >> 6, l = p & 63;
        const int n = l & 15, quad = l >> 4;
        const float* src = w + (t * 16 + n) * NC + cc * 32 + quad * 8;
        const float4 f0 = *(const float4*)src;
        const float4 f1 = *(const float4*)(src + 4);
        union { unsigned short u[8]; uint4 v; } pk;
        pk.u[0] = f2bf(-2.f * f0.x); pk.u[1] = f2bf(-2.f * f0.y);
        pk.u[2] = f2bf(-2.f * f0.z); pk.u[3] = f2bf(-2.f * f0.w);
        pk.u[4] = f2bf(-2.f * f1.x); pk.u[5] = f2bf(-2.f * f1.y);
        pk.u[6] = f2bf(-2.f * f1.z); pk.u[7] = f2bf(-2.f * f1.w);
        *(uint4*)(cb + (size_t)t * 4096 + cc * 512 + (size_t)l * 8) = pk.v;
    }
    if (b == 128) {
#pragma unroll
        for (int i = 0; i < 4; ++i) counts[tid * 4 + i] = 0u;
        if (tid < 2) lossdone[tid] = 0u;
    }
}

// ---------------- K2: main ----------------
__global__ __launch_bounds__(512, 4) void vq_main5(const float* __restrict__ z,
                                                   const float* __restrict__ w,
                                                   const float* __restrict__ wsq,
                                                   const unsigned short* __restrict__ cb,
                                                   unsigned int* __restrict__ counts,
                                                   unsigned int* __restrict__ lossdone,
                                                   float* __restrict__ out) {
    __shared__ __align__(16) char cbuf[2][32768];   // 64 KB double-buffered chunks
    // post-loop aliases in cbuf[0] (chunk 15 reads cbuf[1]):
    int*   fidx  = (int*)(cbuf[0]);            // [0,256)    64 ints
    float* pscr  = (float*)(cbuf[0] + 256);    // [256,1280) [4][64]
    int*   pidx  = (int*)(cbuf[0] + 1280);     // [1280,2304)
    float* zsqs  = (float*)(cbuf[0] + 2304);   // [2304,2560) 64 f32
    int*   lflag = (int*)(cbuf[0] + 2560);
    float* red2  = (float*)(cbuf[0] + 2576);   // [4]

    const int tid  = threadIdx.x;
    const int wv   = tid >> 6, lane = tid & 63;
    const int n    = lane & 15, quad = lane >> 4;
    const int zhalf = wv & 1;         // which 32 z of the block's 64
    const int cq    = wv >> 1;        // which 256 codes (tiles cq*16..+15)
    const int b    = blockIdx.x;
    const int img  = b >> 4;
    const int hw0  = (b & 15) << 6;   // 64 hw per block
    const float* zb = z + (size_t)img * (NC * NHW);
    const char* cbb = (const char*)cb;

    // chunk ch: slot i (8 KB) holds tile (i*16 + ch), i = cq. 512thr x 4 x 16B.
#define STAGE(ch)                                                              \
    {                                                                          \
        _Pragma("unroll")                                                      \
        for (int i = 0; i < 4; ++i) {                                          \
            const char* gsrc = cbb + (size_t)(i * 16 + (ch)) * 8192 + tid * 16;\
            char* ldst = cbuf[(ch) & 1] + i * 8192 + tid * 16;                 \
            __builtin_amdgcn_global_load_lds(                                  \
                (const __attribute__((address_space(1))) unsigned int*)        \
                    (uintptr_t)gsrc,                                           \
                (__attribute__((address_space(3))) unsigned int*)              \
                    (uint32_t)(uintptr_t)ldst,                                 \
                16, 0, 0);                                                     \
        }                                                                      \
    }

    STAGE(0);   // DMA overlaps phase A

    // ---- Phase A: 2 B-sets (32 z) in registers + fp32 ||z||^2 partials ----
    bf16x8 bfr[2][8];
    float zsqp[2] = {0.f, 0.f};
#pragma unroll
    for (int s = 0; s < 2; ++s) {
#pragma unroll
        for (int cc = 0; cc < 8; ++cc) {
            const float* zp = zb + (size_t)(cc * 32 + quad * 8) * NHW
                              + hw0 + zhalf * 32 + s * 16 + n;
            union { unsigned short u[8]; bf16x8 v; } pk;
#pragma unroll
            for (int j = 0; j < 8; ++j) {
                const float f = zp[(size_t)j * NHW];
                zsqp[s] = fmaf(f, f, zsqp[s]);
                pk.u[j] = f2bf(f);
            }
            bfr[s][cc] = pk.v;
        }
    }

    float bestv[2] = {FLT_MAX, FLT_MAX};
    int   besti[2] = {0, 0};

    for (int ch = 0; ch < 16; ++ch) {
        __syncthreads();                    // drains STAGE(ch) DMA
        if (ch + 1 < 16) STAGE(ch + 1);     // prefetch; compute(ch) covers it
        const char* bufc = cbuf[ch & 1];
        const int kt = cq * 256 + ch * 16;
        f32x4 acc0 = *(const f32x4*)(wsq + kt + quad * 4);
        f32x4 acc1 = acc0;
#pragma unroll
        for (int cc = 0; cc < 8; ++cc) {    // 1 A-read feeds 2 MFMAs
            const bf16x8 a = *(const bf16x8*)(bufc + cq * 8192 + cc * 1024 + lane * 16);
            acc0 = __builtin_amdgcn_mfma_f32_16x16x32_bf16(a, bfr[0][cc], acc0, 0, 0, 0);
            acc1 = __builtin_amdgcn_mfma_f32_16x16x32_bf16(a, bfr[1][cc], acc1, 0, 0, 0);
        }
#pragma unroll
        for (int r = 0; r < 4; ++r) {
            const int k = kt + quad * 4 + r;
            if (acc0[r] < bestv[0]) { bestv[0] = acc0[r]; besti[0] = k; }
            if (acc1[r] < bestv[1]) { bestv[1] = acc1[r]; besti[1] = k; }
        }
    }

    // ---- cross-quad reduce: argmin per set + fp32 ||z||^2 sum ----
#pragma unroll
    for (int s = 0; s < 2; ++s) {
        float bv = bestv[s]; int bi = besti[s]; float zs = zsqp[s];
#pragma unroll
        for (int off = 16; off <= 32; off <<= 1) {
            const float ov = __shfl_xor(bv, off, 64);
            const int   ok = __shfl_xor(bi, off, 64);
            if (ov < bv || (ov == bv && ok < bi)) { bv = ov; bi = ok; }
            zs += __shfl_xor(zs, off, 64);
        }
        bestv[s] = bv; besti[s] = bi; zsqp[s] = zs;
    }
    __syncthreads();                  // loop done; cbuf[0] aliases now safe
    if (lane < 16) {
#pragma unroll
        for (int s = 0; s < 2; ++s) {
            const int zloc = zhalf * 32 + s * 16 + lane;
            pscr[cq * 64 + zloc] = bestv[s];
            pidx[cq * 64 + zloc] = besti[s];
            if (cq == 0) zsqs[zloc] = zsqp[s];
        }
    }
    __syncthreads();
    if (tid < 64) {   // combine 4 code-quarters; histogram; loss from scores
        float bv = pscr[tid]; int bi = pidx[tid];
#pragma unroll
        for (int q = 1; q < 4; ++q) {
            const float v = pscr[q * 64 + tid];
            if (v < bv) { bv = v; bi = pidx[q * 64 + tid]; }
        }
        fidx[tid] = bi;
        atomicAdd(&counts[bi], 1u);
        float ln = bv + zsqs[tid];    // == sum_c (q - z)^2 for this vector
#pragma unroll
        for (int off = 32; off; off >>= 1) ln += __shfl_down(ln, off, 64);
        if (tid == 0) {
            atomicAdd((float*)lossdone, ln);
            const unsigned old = __hip_atomic_fetch_add(&lossdone[1], 1u,
                                     __ATOMIC_ACQ_REL, __HIP_MEMORY_SCOPE_AGENT);
            lflag[0] = (old == GRID_MAIN - 1) ? 1 : 0;
        }
    }
    __syncthreads();   // fidx + lflag visible to all

    // ---- Phase 2: gather codebook rows, stream out (no z re-read) ----
    {
        const int hwl = tid & 63;
        const int cg  = tid >> 6;          // c range [cg*32, cg*32+32)
        const int myk = fidx[hwl];
        const float* wr = w + myk * NC + cg * 32;
        float* ob = out + (size_t)img * (NC * NHW) + (size_t)(cg * 32) * NHW + hw0 + hwl;
#pragma unroll
        for (int p = 0; p < 8; ++p) {
            const float4 q4 = *(const float4*)(wr + p * 4);
            ob[(size_t)(p * 4 + 0) * NHW] = q4.x;
            ob[(size_t)(p * 4 + 1) * NHW] = q4.y;
            ob[(size_t)(p * 4 + 2) * NHW] = q4.z;
            ob[(size_t)(p * 4 + 3) * NHW] = q4.w;
        }
    }
    __syncthreads();
    if (lflag[0]) {   // last block: loss + perplexity
        if (tid < 256) {
            float s = 0.f;
#pragma unroll
            for (int p = 0; p < 4; ++p) {
                const unsigned c = __hip_atomic_load(&counts[tid + p * 256],
                                       __ATOMIC_RELAXED, __HIP_MEMORY_SCOPE_AGENT);
                const float pr = (float)c * (1.f / 32768.f);
                s = fmaf(pr, logf(pr + 1e-10f), s);
            }
#pragma unroll
            for (int off = 32; off; off >>= 1) s += __shfl_down(s, off, 64);
            if (lane == 0) red2[tid >> 6] = s;
        }
        __syncthreads();
        if (tid == 0) {
            const float tot = red2[0] + red2[1] + red2[2] + red2[3];
            const float ls = __hip_atomic_load((float*)lossdone,
                                 __ATOMIC_RELAXED, __HIP_MEMORY_SCOPE_AGENT);
            out[NELEM]     = ls * (1.25f / (float)NELEM);
            out[NELEM + 1] = expf(-tot);
        }
    }
}

extern "C" void kernel_launch(void* const* d_in, const int* in_sizes, int n_in,
                              void* d_out, int out_size, void* d_ws, size_t ws_size,
                              hipStream_t stream) {
    const float* z = (const float*)d_in[0];
    const float* w = (const float*)d_in[1];
    float* out = (float*)d_out;

    float*          wsq      = (float*)d_ws;
    unsigned int*   counts   = (unsigned int*)((char*)d_ws + 4096);
    unsigned int*   lossdone = (unsigned int*)((char*)d_ws + 8192);
    unsigned short* cbfrag   = (unsigned short*)((char*)d_ws + 16384);  // 512 KB

    vq_prep <<<256,       256, 0, stream>>>(w, wsq, cbfrag, counts, lossdone);
    vq_main5<<<GRID_MAIN, 512, 0, stream>>>(z, w, wsq, cbfrag, counts, lossdone, out);
}

// Round 6
// 153.704 us; speedup vs baseline: 1.1325x; 1.1325x over previous
//
#include <hip/hip_runtime.h>
#include <float.h>
#include <math.h>
#include <stdint.h>

// VQ-VAE VectorQuantizer — round 6: barrier-free K-loop, A-frags direct from
// L2 (no LDS staging, no __syncthreads in the scan), no launch-bounds min-waves
// (R4/R5: min-waves + MFMA => arch/acc VGPR split 64/64 => scratch spills).
//
// vq_main6: grid 1024 x 256thr (4 waves). Block = 32 z. Wave cq in 0..3 scans
//   codes [cq*256, cq*256+256) reading packed A-frags straight from global
//   (512 KB codebook, L2-hot across all 1024 blocks). 2 B-sets (32 z) in regs.
//   score[k][n] = wsq[k] - 2 w_k.z_n (MFMA);  loss_n = min_score + ||z_n||^2.
//
// ws: [0,4096) wsq f32 | [4096,8192) counts u32 | [8192,8200) loss f32, done u32
//     [16384, +524288) cbfrag bf16

#define NB   32
#define NC   256
#define NHW  1024
#define NK   1024
#define NELEM (NB*NC*NHW)
#define GRID_MAIN 1024

typedef __attribute__((ext_vector_type(8))) short bf16x8;
typedef __attribute__((ext_vector_type(4))) float f32x4;

__device__ __forceinline__ unsigned short f2bf(float f) {   // RTN fp32->bf16
    unsigned u = __float_as_uint(f);
    u += 0x7FFFu + ((u >> 16) & 1u);
    return (unsigned short)(u >> 16);
}

// ---------------- K1: prep = wsq + pack + zero ----------------
__global__ __launch_bounds__(256) void vq_prep(const float* __restrict__ w,
                                               float* __restrict__ wsq,
                                               unsigned short* __restrict__ cb,
                                               unsigned int* __restrict__ counts,
                                               unsigned int* __restrict__ lossdone) {
    const int tid = threadIdx.x, b = blockIdx.x;
    const int lane = tid & 63, wv = tid >> 6;
    {   // wsq for code k = b*4 + wv
        const int k = b * 4 + wv;
        const float* row = w + k * NC;
        float s = 0.f;
#pragma unroll
        for (int p = 0; p < 4; ++p) { float v = row[lane + p * 64]; s = fmaf(v, v, s); }
#pragma unroll
        for (int off = 32; off; off >>= 1) s += __shfl_down(s, off, 64);
        if (lane == 0) wsq[k] = s;
    }
    // pack one 16B A-frag piece per thread (blocks 0..127):
    // tile t, lane l holds A[m=l&15][k=cc*32+(l>>4)*8+j], j=0..7, scaled by -2
    const int gt = b * 256 + tid;
    if (gt < 32768) {
        const int t = gt >> 9, p = gt & 511;
        const int cc = p >> 6, l = p & 63;
        const int n = l & 15, quad = l >> 4;
        const float* src = w + (t * 16 + n) * NC + cc * 32 + quad * 8;
        const float4 f0 = *(const float4*)src;
        const float4 f1 = *(const float4*)(src + 4);
        union { unsigned short u[8]; uint4 v; } pk;
        pk.u[0] = f2bf(-2.f * f0.x); pk.u[1] = f2bf(-2.f * f0.y);
        pk.u[2] = f2bf(-2.f * f0.z); pk.u[3] = f2bf(-2.f * f0.w);
        pk.u[4] = f2bf(-2.f * f1.x); pk.u[5] = f2bf(-2.f * f1.y);
        pk.u[6] = f2bf(-2.f * f1.z); pk.u[7] = f2bf(-2.f * f1.w);
        *(uint4*)(cb + (size_t)t * 4096 + cc * 512 + (size_t)l * 8) = pk.v;
    }
    if (b == 128) {
#pragma unroll
        for (int i = 0; i < 4; ++i) counts[tid * 4 + i] = 0u;
        if (tid < 2) lossdone[tid] = 0u;
    }
}

// ---------------- K2: main ----------------
__global__ __launch_bounds__(256) void vq_main6(const float* __restrict__ z,
                                                const float* __restrict__ w,
                                                const float* __restrict__ wsq,
                                                const unsigned short* __restrict__ cb,
                                                unsigned int* __restrict__ counts,
                                                unsigned int* __restrict__ lossdone,
                                                float* __restrict__ out) {
    __shared__ float pscr[4][32];
    __shared__ int   pidx[4][32];
    __shared__ int   fidx[32];
    __shared__ float zsqs[32];
    __shared__ int   lflag[1];
    __shared__ float red2[4];

    const int tid  = threadIdx.x;
    const int cq   = tid >> 6, lane = tid & 63;   // cq = code quarter
    const int n    = lane & 15, quad = lane >> 4;
    const int b    = blockIdx.x;
    const int img  = b >> 5;
    const int hw0  = (b & 31) << 5;   // 32 hw per block
    const float* zb = z + (size_t)img * (NC * NHW);

    // ---- Phase A: 2 B-sets (32 z) in registers + fp32 ||z||^2 partials ----
    // (all 4 waves load the same 32 z; L1 serves the repeats)
    bf16x8 bfr[2][8];
    float zsqp[2] = {0.f, 0.f};
#pragma unroll
    for (int s = 0; s < 2; ++s) {
#pragma unroll
        for (int cc = 0; cc < 8; ++cc) {
            const float* zp = zb + (size_t)(cc * 32 + quad * 8) * NHW
                              + hw0 + s * 16 + n;
            union { unsigned short u[8]; bf16x8 v; } pk;
#pragma unroll
            for (int j = 0; j < 8; ++j) {
                const float f = zp[(size_t)j * NHW];
                zsqp[s] = fmaf(f, f, zsqp[s]);
                pk.u[j] = f2bf(f);
            }
            bfr[s][cc] = pk.v;
        }
    }

    // ---- barrier-free K-loop: A-frags straight from global (L2-hot) ----
    const char* ap = (const char*)cb + (size_t)(cq * 16) * 8192 + (size_t)lane * 16;
    const float* wsb = wsq + cq * 256 + quad * 4;
    float bestv[2] = {FLT_MAX, FLT_MAX};
    int   besti[2] = {0, 0};

#pragma unroll 2
    for (int t = 0; t < 16; ++t) {
        const int kt = cq * 256 + t * 16;
        f32x4 acc0 = *(const f32x4*)(wsb + t * 16);
        f32x4 acc1 = acc0;
#pragma unroll
        for (int cc = 0; cc < 8; ++cc) {   // 1 L2 A-read feeds 2 MFMAs
            const bf16x8 a = *(const bf16x8*)(ap + t * 8192 + cc * 1024);
            acc0 = __builtin_amdgcn_mfma_f32_16x16x32_bf16(a, bfr[0][cc], acc0, 0, 0, 0);
            acc1 = __builtin_amdgcn_mfma_f32_16x16x32_bf16(a, bfr[1][cc], acc1, 0, 0, 0);
        }
#pragma unroll
        for (int r = 0; r < 4; ++r) {
            const int k = kt + quad * 4 + r;
            if (acc0[r] < bestv[0]) { bestv[0] = acc0[r]; besti[0] = k; }
            if (acc1[r] < bestv[1]) { bestv[1] = acc1[r]; besti[1] = k; }
        }
    }

    // ---- cross-quad reduce: argmin per set + fp32 ||z||^2 sum ----
#pragma unroll
    for (int s = 0; s < 2; ++s) {
        float bv = bestv[s]; int bi = besti[s]; float zs = zsqp[s];
#pragma unroll
        for (int off = 16; off <= 32; off <<= 1) {
            const float ov = __shfl_xor(bv, off, 64);
            const int   ok = __shfl_xor(bi, off, 64);
            if (ov < bv || (ov == bv && ok < bi)) { bv = ov; bi = ok; }
            zs += __shfl_xor(zs, off, 64);
        }
        if (lane < 16) {
            pscr[cq][s * 16 + lane] = bv;
            pidx[cq][s * 16 + lane] = bi;
            if (cq == 0) zsqs[s * 16 + lane] = zs;
        }
    }
    __syncthreads();
    if (tid < 32) {   // combine 4 code-quarters; histogram; loss from scores
        float bv = pscr[0][tid]; int bi = pidx[0][tid];
#pragma unroll
        for (int q = 1; q < 4; ++q) {
            const float v = pscr[q][tid];
            if (v < bv) { bv = v; bi = pidx[q][tid]; }
        }
        fidx[tid] = bi;
        atomicAdd(&counts[bi], 1u);
        float ln = bv + zsqs[tid];    // == sum_c (q - z)^2 for this vector
#pragma unroll
        for (int off = 16; off; off >>= 1) ln += __shfl_down(ln, off, 64);
        if (tid == 0) {
            atomicAdd((float*)lossdone, ln);
            const unsigned old = __hip_atomic_fetch_add(&lossdone[1], 1u,
                                     __ATOMIC_ACQ_REL, __HIP_MEMORY_SCOPE_AGENT);
            lflag[0] = (old == GRID_MAIN - 1) ? 1 : 0;
        }
    }
    __syncthreads();   // fidx + lflag visible

    // ---- Phase 2: gather codebook rows, stream out (no z re-read) ----
    {
        const int hwl = tid & 31;
        const int cg  = tid >> 5;          // c range [cg*32, cg*32+32)
        const int myk = fidx[hwl];
        const float* wr = w + myk * NC + cg * 32;
        float* ob = out + (size_t)img * (NC * NHW) + (size_t)(cg * 32) * NHW + hw0 + hwl;
#pragma unroll
        for (int p = 0; p < 8; ++p) {
            const float4 q4 = *(const float4*)(wr + p * 4);
            ob[(size_t)(p * 4 + 0) * NHW] = q4.x;
            ob[(size_t)(p * 4 + 1) * NHW] = q4.y;
            ob[(size_t)(p * 4 + 2) * NHW] = q4.z;
            ob[(size_t)(p * 4 + 3) * NHW] = q4.w;
        }
    }
    __syncthreads();
    if (lflag[0]) {   // last block: loss + perplexity
        float s = 0.f;
#pragma unroll
        for (int p = 0; p < 4; ++p) {
            const unsigned c = __hip_atomic_load(&counts[tid + p * 256],
                                   __ATOMIC_RELAXED, __HIP_MEMORY_SCOPE_AGENT);
            const float pr = (float)c * (1.f / 32768.f);
            s = fmaf(pr, logf(pr + 1e-10f), s);
        }
#pragma unroll
        for (int off = 32; off; off >>= 1) s += __shfl_down(s, off, 64);
        if (lane == 0) red2[tid >> 6] = s;
        __syncthreads();
        if (tid == 0) {
            const float tot = red2[0] + red2[1] + red2[2] + red2[3];
            const float ls = __hip_atomic_load((float*)lossdone,
                                 __ATOMIC_RELAXED, __HIP_MEMORY_SCOPE_AGENT);
            out[NELEM]     = ls * (1.25f / (float)NELEM);
            out[NELEM + 1] = expf(-tot);
        }
    }
}

extern "C" void kernel_launch(void* const* d_in, const int* in_sizes, int n_in,
                              void* d_out, int out_size, void* d_ws, size_t ws_size,
                              hipStream_t stream) {
    const float* z = (const float*)d_in[0];
    const float* w = (const float*)d_in[1];
    float* out = (float*)d_out;

    float*          wsq      = (float*)d_ws;
    unsigned int*   counts   = (unsigned int*)((char*)d_ws + 4096);
    unsigned int*   lossdone = (unsigned int*)((char*)d_ws + 8192);
    unsigned short* cbfrag   = (unsigned short*)((char*)d_ws + 16384);  // 512 KB

    vq_prep <<<256,       256, 0, stream>>>(w, wsq, cbfrag, counts, lossdone);
    vq_main6<<<GRID_MAIN, 256, 0, stream>>>(z, w, wsq, cbfrag, counts, lossdone, out);
}

// Round 7
// 134.225 us; speedup vs baseline: 1.2969x; 1.1451x over previous
//
#include <hip/hip_runtime.h>
#include <float.h>
#include <math.h>
#include <stdint.h>

// VQ-VAE VectorQuantizer — round 7: R5 structure, spill fixed.
//
// R4/R5 post-mortem: __launch_bounds__(..., min_waves) with MFMA forced a
// 64/64 arch/acc VGPR split -> scratch spills (+95MB WRITE, +38MB FETCH).
// R6 (no min-waves) compiled the same live set to VGPR=124, zero spill.
// R7 = R5's LDS-staged 8-wave structure with plain __launch_bounds__(512).
//
// vq_main7: grid 512 x 512thr. Block = 64 z, 2 blocks/CU (64KB dbuf).
//   Wave (zhalf, cq): 32 z (2 B-sets) x 256 codes. Chunk = 4 tiles = 32 KB,
//   double-buffered global_load_lds DMA.
//   score[k][n] = wsq[k] - 2 w_k.z_n (MFMA);  loss_n = min_score + ||z_n||^2.
//
// ws: [0,4096) wsq f32 | [4096,8192) counts u32 | [8192,8200) loss f32, done u32
//     [16384, +524288) cbfrag bf16

#define NB   32
#define NC   256
#define NHW  1024
#define NK   1024
#define NELEM (NB*NC*NHW)
#define GRID_MAIN 512

typedef __attribute__((ext_vector_type(8))) short bf16x8;
typedef __attribute__((ext_vector_type(4))) float f32x4;

__device__ __forceinline__ unsigned short f2bf(float f) {   // RTN fp32->bf16
    unsigned u = __float_as_uint(f);
    u += 0x7FFFu + ((u >> 16) & 1u);
    return (unsigned short)(u >> 16);
}

// ---------------- K1: prep = wsq + pack + zero ----------------
__global__ __launch_bounds__(256) void vq_prep(const float* __restrict__ w,
                                               float* __restrict__ wsq,
                                               unsigned short* __restrict__ cb,
                                               unsigned int* __restrict__ counts,
                                               unsigned int* __restrict__ lossdone) {
    const int tid = threadIdx.x, b = blockIdx.x;
    const int lane = tid & 63, wv = tid >> 6;
    {   // wsq for code k = b*4 + wv
        const int k = b * 4 + wv;
        const float* row = w + k * NC;
        float s = 0.f;
#pragma unroll
        for (int p = 0; p < 4; ++p) { float v = row[lane + p * 64]; s = fmaf(v, v, s); }
#pragma unroll
        for (int off = 32; off; off >>= 1) s += __shfl_down(s, off, 64);
        if (lane == 0) wsq[k] = s;
    }
    // pack one 16B A-frag piece per thread (blocks 0..127):
    // tile t, lane l holds A[m=l&15][k=cc*32+(l>>4)*8+j], j=0..7, scaled by -2
    const int gt = b * 256 + tid;
    if (gt < 32768) {
        const int t = gt >> 9, p = gt & 511;
        const int cc = p >> 6, l = p & 63;
        const int n = l & 15, quad = l >> 4;
        const float* src = w + (t * 16 + n) * NC + cc * 32 + quad * 8;
        const float4 f0 = *(const float4*)src;
        const float4 f1 = *(const float4*)(src + 4);
        union { unsigned short u[8]; uint4 v; } pk;
        pk.u[0] = f2bf(-2.f * f0.x); pk.u[1] = f2bf(-2.f * f0.y);
        pk.u[2] = f2bf(-2.f * f0.z); pk.u[3] = f2bf(-2.f * f0.w);
        pk.u[4] = f2bf(-2.f * f1.x); pk.u[5] = f2bf(-2.f * f1.y);
        pk.u[6] = f2bf(-2.f * f1.z); pk.u[7] = f2bf(-2.f * f1.w);
        *(uint4*)(cb + (size_t)t * 4096 + cc * 512 + (size_t)l * 8) = pk.v;
    }
    if (b == 128) {
#pragma unroll
        for (int i = 0; i < 4; ++i) counts[tid * 4 + i] = 0u;
        if (tid < 2) lossdone[tid] = 0u;
    }
}

// ---------------- K2: main ----------------
__global__ __launch_bounds__(512) void vq_main7(const float* __restrict__ z,
                                                const float* __restrict__ w,
                                                const float* __restrict__ wsq,
                                                const unsigned short* __restrict__ cb,
                                                unsigned int* __restrict__ counts,
                                                unsigned int* __restrict__ lossdone,
                                                float* __restrict__ out) {
    __shared__ __align__(16) char cbuf[2][32768];   // 64 KB double-buffered chunks
    // post-loop aliases in cbuf[0] (chunk 15 reads cbuf[1]):
    int*   fidx  = (int*)(cbuf[0]);            // [0,256)    64 ints
    float* pscr  = (float*)(cbuf[0] + 256);    // [256,1280) [4][64]
    int*   pidx  = (int*)(cbuf[0] + 1280);     // [1280,2304)
    float* zsqs  = (float*)(cbuf[0] + 2304);   // [2304,2560) 64 f32
    int*   lflag = (int*)(cbuf[0] + 2560);
    float* red2  = (float*)(cbuf[0] + 2576);   // [8]

    const int tid  = threadIdx.x;
    const int wv   = tid >> 6, lane = tid & 63;
    const int n    = lane & 15, quad = lane >> 4;
    const int zhalf = wv & 1;         // which 32 z of the block's 64
    const int cq    = wv >> 1;        // which 256 codes (tiles cq*16..+15)
    const int b    = blockIdx.x;
    const int img  = b >> 4;
    const int hw0  = (b & 15) << 6;   // 64 hw per block
    const float* zb = z + (size_t)img * (NC * NHW);
    const char* cbb = (const char*)cb;

    // chunk ch: slot i (8 KB) holds tile (i*16 + ch), i = cq. 512thr x 4 x 16B.
#define STAGE(ch)                                                              \
    {                                                                          \
        _Pragma("unroll")                                                      \
        for (int i = 0; i < 4; ++i) {                                          \
            const char* gsrc = cbb + (size_t)(i * 16 + (ch)) * 8192 + tid * 16;\
            char* ldst = cbuf[(ch) & 1] + i * 8192 + tid * 16;                 \
            __builtin_amdgcn_global_load_lds(                                  \
                (const __attribute__((address_space(1))) unsigned int*)        \
                    (uintptr_t)gsrc,                                           \
                (__attribute__((address_space(3))) unsigned int*)              \
                    (uint32_t)(uintptr_t)ldst,                                 \
                16, 0, 0);                                                     \
        }                                                                      \
    }

    STAGE(0);   // DMA overlaps phase A

    // ---- Phase A: 2 B-sets (32 z) in registers + fp32 ||z||^2 partials ----
    bf16x8 bfr[2][8];
    float zsqp[2] = {0.f, 0.f};
#pragma unroll
    for (int s = 0; s < 2; ++s) {
#pragma unroll
        for (int cc = 0; cc < 8; ++cc) {
            const float* zp = zb + (size_t)(cc * 32 + quad * 8) * NHW
                              + hw0 + zhalf * 32 + s * 16 + n;
            union { unsigned short u[8]; bf16x8 v; } pk;
#pragma unroll
            for (int j = 0; j < 8; ++j) {
                const float f = zp[(size_t)j * NHW];
                zsqp[s] = fmaf(f, f, zsqp[s]);
                pk.u[j] = f2bf(f);
            }
            bfr[s][cc] = pk.v;
        }
    }

    float bestv[2] = {FLT_MAX, FLT_MAX};
    int   besti[2] = {0, 0};

    for (int ch = 0; ch < 16; ++ch) {
        __syncthreads();                    // drains STAGE(ch) DMA
        if (ch + 1 < 16) STAGE(ch + 1);     // prefetch; compute(ch) covers it
        const char* bufc = cbuf[ch & 1];
        const int kt = cq * 256 + ch * 16;
        f32x4 acc0 = *(const f32x4*)(wsq + kt + quad * 4);
        f32x4 acc1 = acc0;
#pragma unroll
        for (int cc = 0; cc < 8; ++cc) {    // 1 A-read feeds 2 MFMAs
            const bf16x8 a = *(const bf16x8*)(bufc + cq * 8192 + cc * 1024 + lane * 16);
            acc0 = __builtin_amdgcn_mfma_f32_16x16x32_bf16(a, bfr[0][cc], acc0, 0, 0, 0);
            acc1 = __builtin_amdgcn_mfma_f32_16x16x32_bf16(a, bfr[1][cc], acc1, 0, 0, 0);
        }
#pragma unroll
        for (int r = 0; r < 4; ++r) {
            const int k = kt + quad * 4 + r;
            if (acc0[r] < bestv[0]) { bestv[0] = acc0[r]; besti[0] = k; }
            if (acc1[r] < bestv[1]) { bestv[1] = acc1[r]; besti[1] = k; }
        }
    }

    // ---- cross-quad reduce: argmin per set + fp32 ||z||^2 sum ----
#pragma unroll
    for (int s = 0; s < 2; ++s) {
        float bv = bestv[s]; int bi = besti[s]; float zs = zsqp[s];
#pragma unroll
        for (int off = 16; off <= 32; off <<= 1) {
            const float ov = __shfl_xor(bv, off, 64);
            const int   ok = __shfl_xor(bi, off, 64);
            if (ov < bv || (ov == bv && ok < bi)) { bv = ov; bi = ok; }
            zs += __shfl_xor(zs, off, 64);
        }
        bestv[s] = bv; besti[s] = bi; zsqp[s] = zs;
    }
    __syncthreads();                  // loop done; cbuf[0] aliases now safe
    if (lane < 16) {
#pragma unroll
        for (int s = 0; s < 2; ++s) {
            const int zloc = zhalf * 32 + s * 16 + lane;
            pscr[cq * 64 + zloc] = bestv[s];
            pidx[cq * 64 + zloc] = besti[s];
            if (cq == 0) zsqs[zloc] = zsqp[s];
        }
    }
    __syncthreads();
    if (tid < 64) {   // combine 4 code-quarters; histogram; loss from scores
        float bv = pscr[tid]; int bi = pidx[tid];
#pragma unroll
        for (int q = 1; q < 4; ++q) {
            const float v = pscr[q * 64 + tid];
            if (v < bv) { bv = v; bi = pidx[q * 64 + tid]; }
        }
        fidx[tid] = bi;
        atomicAdd(&counts[bi], 1u);
        float ln = bv + zsqs[tid];    // == sum_c (q - z)^2 for this vector
#pragma unroll
        for (int off = 32; off; off >>= 1) ln += __shfl_down(ln, off, 64);
        if (tid == 0) {
            atomicAdd((float*)lossdone, ln);
            const unsigned old = __hip_atomic_fetch_add(&lossdone[1], 1u,
                                     __ATOMIC_ACQ_REL, __HIP_MEMORY_SCOPE_AGENT);
            lflag[0] = (old == GRID_MAIN - 1) ? 1 : 0;
        }
    }
    __syncthreads();   // fidx + lflag visible to all

    // ---- Phase 2: gather codebook rows, stream out (no z re-read) ----
    {
        const int hwl = tid & 63;
        const int cg  = tid >> 6;          // c range [cg*32, cg*32+32)
        const int myk = fidx[hwl];
        const float* wr = w + myk * NC + cg * 32;
        float* ob = out + (size_t)img * (NC * NHW) + (size_t)(cg * 32) * NHW + hw0 + hwl;
#pragma unroll
        for (int p = 0; p < 8; ++p) {
            const float4 q4 = *(const float4*)(wr + p * 4);
            ob[(size_t)(p * 4 + 0) * NHW] = q4.x;
            ob[(size_t)(p * 4 + 1) * NHW] = q4.y;
            ob[(size_t)(p * 4 + 2) * NHW] = q4.z;
            ob[(size_t)(p * 4 + 3) * NHW] = q4.w;
        }
    }
    __syncthreads();
    if (lflag[0]) {   // last block: loss + perplexity
        if (tid < 256) {
            float s = 0.f;
#pragma unroll
            for (int p = 0; p < 4; ++p) {
                const unsigned c = __hip_atomic_load(&counts[tid + p * 256],
                                       __ATOMIC_RELAXED, __HIP_MEMORY_SCOPE_AGENT);
                const float pr = (float)c * (1.f / 32768.f);
                s = fmaf(pr, logf(pr + 1e-10f), s);
            }
#pragma unroll
            for (int off = 32; off; off >>= 1) s += __shfl_down(s, off, 64);
            if (lane == 0) red2[tid >> 6] = s;
        }
        __syncthreads();
        if (tid == 0) {
            const float tot = red2[0] + red2[1] + red2[2] + red2[3];
            const float ls = __hip_atomic_load((float*)lossdone,
                                 __ATOMIC_RELAXED, __HIP_MEMORY_SCOPE_AGENT);
            out[NELEM]     = ls * (1.25f / (float)NELEM);
            out[NELEM + 1] = expf(-tot);
        }
    }
}

extern "C" void kernel_launch(void* const* d_in, const int* in_sizes, int n_in,
                              void* d_out, int out_size, void* d_ws, size_t ws_size,
                              hipStream_t stream) {
    const float* z = (const float*)d_in[0];
    const float* w = (const float*)d_in[1];
    float* out = (float*)d_out;

    float*          wsq      = (float*)d_ws;
    unsigned int*   counts   = (unsigned int*)((char*)d_ws + 4096);
    unsigned int*   lossdone = (unsigned int*)((char*)d_ws + 8192);
    unsigned short* cbfrag   = (unsigned short*)((char*)d_ws + 16384);  // 512 KB

    vq_prep <<<256,       256, 0, stream>>>(w, wsq, cbfrag, counts, lossdone);
    vq_main7<<<GRID_MAIN, 512, 0, stream>>>(z, w, wsq, cbfrag, counts, lossdone, out);
}